// Round 8
// baseline (461.079 us; speedup 1.0000x reference)
//
#include <hip/hip_runtime.h>
#include <hip/hip_bf16.h>
#include <cstddef>

// K=2048, B=4, D=5, ATOM=125, BOND=12, HID=125, OUT=40
// NOFF = [0, 2048, 10240, 43008, 175104, 699392]
// BOFF = [0, 8192, 40960, 172032, 696320]
//
// Fully-fused tree, barrier-minimal build (r6 math, new data paths):
//  - one block per root; passes L0,D0,L1,D1,d2,d1,d0; ONE barrier per pass
//  - X fragments: global -> registers directly (8 consecutive floats/lane,
//    cvt_pkrtz to f16); no X LDS staging, no per-chunk barriers
//  - W1 fragments: direct 16B dwordx4 from pre-packed w1f [hid][192] f16
//    (48 KB, L1/L2-resident; k' = kc*32 + l16*8 + j is contiguous in memory)
//  - child outputs in LDS, [row][56] f16 (2-way bank aliasing = free)
//  - layer2 from registers, W2 frag-packed (r3/r6-validated mapping)
//  - k' layout (192): [0,125) msg, [125,128) 0, [128,140) bond, [140,144) 0,
//    [144,184) child, [184,192) 0

typedef __attribute__((ext_vector_type(8))) _Float16 h8;
typedef __attribute__((ext_vector_type(4))) float f32x4;
typedef __attribute__((ext_vector_type(4))) unsigned int v4u;

static constexpr int HID = 125, OUT = 40;
static constexpr int CLDS = 56;  // child-buffer row stride in f16 elements

template <int N> struct ic { static constexpr int v = N; };

__device__ __forceinline__ unsigned short f2h(float x) {
    _Float16 h = (_Float16)x;
    return __builtin_bit_cast(unsigned short, h);
}
__device__ __forceinline__ unsigned int pkrtz(float a, float b) {
    return __builtin_bit_cast(unsigned int, __builtin_amdgcn_cvt_pkrtz(a, b));
}

// W1 plane: [128 hid][192 k'] f16, k' remapped per layout above.
__global__ void prep_w1(const float* __restrict__ W1, unsigned short* __restrict__ w1f) {
    int idx = blockIdx.x * 256 + threadIdx.x;
    if (idx >= 128 * 192) return;
    int hid = idx / 192, kp = idx % 192;
    int k = (kp < 125) ? kp
          : (kp >= 128 && kp < 140) ? kp - 3
          : (kp >= 144 && kp < 184) ? kp - 7 : -1;
    float v = (k >= 0 && hid < HID) ? W1[(size_t)k * HID + hid] : 0.f;
    w1f[idx] = f2h(v);
}

// W2 frag-packed (layer2 B), validated mapping:
// frag fr = kt*3+qt; lane ln; elem j: hid = kt*32 + 16*(j>>2) + (ln>>4)*4 + (j&3),
// q = qt*16 + (ln&15). 4 u32 per (fr,lane).
__global__ void prep_w2(const float* __restrict__ W2, unsigned int* __restrict__ w2f) {
    int t = threadIdx.x;
    for (int task = t; task < 12 * 64; task += 256) {
        int ln = task & 63, fr = task >> 6;
        int kt = fr / 3, qt = fr % 3;
        int q = qt * 16 + (ln & 15);
        unsigned int w[4];
#pragma unroll
        for (int jp = 0; jp < 4; jp++) {
            unsigned short e[2];
#pragma unroll
            for (int s = 0; s < 2; s++) {
                int j = jp * 2 + s;
                int hid = kt * 32 + ((j >> 2) << 4) + ((ln >> 4) << 2) + (j & 3);
                float v = (hid < HID && q < OUT) ? W2[(size_t)hid * OUT + q] : 0.f;
                e[s] = f2h(v);
            }
            w[jp] = (unsigned int)e[0] | ((unsigned int)e[1] << 16);
        }
        v4u val = {w[0], w[1], w[2], w[3]};
        ((v4u*)w2f)[fr * 64 + ln] = val;
    }
}

struct Desc {
    int msgRow;
    int bondRow;
    int leaf;
};

__global__ void __launch_bounds__(256, 3)
tree_mlp(const float* __restrict__ node_msg, const float* __restrict__ bonds,
         const unsigned short* __restrict__ w1f,
         const unsigned int* __restrict__ w2f,
         const float* __restrict__ b1, const float* __restrict__ b2,
         float* __restrict__ out) {
    __shared__ __align__(16) unsigned short lout[128 * CLDS];  // leaf outs
    __shared__ __align__(16) unsigned short d3o[64 * CLDS];    // d3-parent outs
    __shared__ __align__(16) unsigned short d2o[16 * CLDS];
    __shared__ __align__(16) unsigned short d1o[16 * CLDS];

    const int tid = threadIdx.x;
    const int lane = tid & 63;
    const int wv = tid >> 6;
    const int l15 = tid & 15;
    const int l16 = (tid >> 4) & 3;
    const int b = blockIdx.x;

    // d1o rows 4..15 are read (as zeros) by the d0 pass — init the buffer.
    for (int i = tid; i < 16 * CLDS; i += 256) d1o[i] = 0;

    const Desc dL0{175104 + 256 * b, 0, 1};
    const Desc dL1{175104 + 256 * b + 128, 0, 1};
    const Desc dD0{43008 + 64 * b, 172032 + 256 * b, 0};
    const Desc dD1{43008 + 64 * b + 32, 172032 + 256 * b + 128, 0};
    const Desc dd2{10240 + 16 * b, 40960 + 64 * b, 0};
    const Desc dd1{2048 + 4 * b, 8192 + 16 * b, 0};
    const Desc dd0{b, 4 * b, 0};

    // MODE 0: per-row out -> cdst[row]; MODE 1: sibling-sum -> cdst[pbase+p];
    // MODE 2: sibling-sum -> gout (final, parent 0 only).
    auto run_pass = [&](auto RC, auto NCC, auto MC, const Desc& cur,
                        const unsigned short* csrc, unsigned short* cdst,
                        int pbase, float* gout) {
        constexpr int R = decltype(RC)::v;
        constexpr int NCv = decltype(NCC)::v;
        constexpr int MODE = decltype(MC)::v;
        constexpr int NT = (R == 128) ? 2 : 1;
        const bool act = (R >= 64) || (wv == 0);

        if (act) {
            f32x4 acc[8][NT];
#pragma unroll
            for (int mt = 0; mt < 8; mt++) {
                f32x4 bi;
#pragma unroll
                for (int r = 0; r < 4; r++) {
                    int h_ = mt * 16 + l16 * 4 + r;
                    bi[r] = (h_ < HID) ? b1[h_] : 0.f;
                }
#pragma unroll
                for (int nt = 0; nt < NT; nt++) acc[mt][nt] = bi;
            }

            // ---- layer 1: straight-line loads + MFMA, no barriers ----
#pragma unroll
            for (int kc = 0; kc < NCv; ++kc) {
                h8 xf[NT];
#pragma unroll
                for (int nt = 0; nt < NT; ++nt) {
                    const int tile = (R == 128) ? wv * 32 + nt * 16
                                  : (R == 64) ? wv * 16 : 0;
                    const int r = tile + l15;
                    if (kc < 4) {
                        const int mr = cur.leaf ? r : (r >> 2);
                        const float* mp = node_msg + (size_t)(cur.msgRow + mr) * 125;
                        const int k0 = kc * 32 + l16 * 8;
                        float t[8];
#pragma unroll
                        for (int j = 0; j < 8; j++) {
                            int k = k0 + j;
                            t[j] = (k < 125) ? mp[k] : 0.f;
                        }
                        v4u xv = {pkrtz(t[0], t[1]), pkrtz(t[2], t[3]),
                                  pkrtz(t[4], t[5]), pkrtz(t[6], t[7])};
                        xf[nt] = __builtin_bit_cast(h8, xv);
                    } else if (kc == 4) {
                        if (l16 < 2) {
                            const float* bp = bonds + (size_t)(cur.bondRow + r) * 12;
                            const int c0 = l16 * 8;
                            float t[8];
#pragma unroll
                            for (int j = 0; j < 8; j++) {
                                int c = c0 + j;
                                t[j] = (c < 12) ? bp[c] : 0.f;
                            }
                            v4u xv = {pkrtz(t[0], t[1]), pkrtz(t[2], t[3]),
                                      pkrtz(t[4], t[5]), pkrtz(t[6], t[7])};
                            xf[nt] = __builtin_bit_cast(h8, xv);
                        } else {
                            xf[nt] = *(const h8*)&csrc[r * CLDS + (l16 - 2) * 8];
                        }
                    } else {  // kc == 5: child cols 16..39 (l16<3), else zero
                        if (l16 < 3) {
                            xf[nt] = *(const h8*)&csrc[r * CLDS + (l16 + 2) * 8];
                        } else {
                            h8 z = {};
                            xf[nt] = z;
                        }
                    }
                }
#pragma unroll
                for (int mt = 0; mt < 8; ++mt) {
                    h8 wf = *(const h8*)&w1f[(size_t)(mt * 16 + l15) * 192 + kc * 32 + l16 * 8];
#pragma unroll
                    for (int nt = 0; nt < NT; ++nt)
                        acc[mt][nt] = __builtin_amdgcn_mfma_f32_16x16x32_f16(
                            wf, xf[nt], acc[mt][nt], 0, 0, 0);
                }
            }

            // ---- leaky_relu on h ----
#pragma unroll
            for (int mt = 0; mt < 8; mt++)
#pragma unroll
                for (int nt = 0; nt < NT; nt++)
#pragma unroll
                    for (int r = 0; r < 4; r++)
                        acc[mt][nt][r] = fmaxf(acc[mt][nt][r], 0.01f * acc[mt][nt][r]);

            // ---- layer 2 (registers only) ----
            float b2v[3];
#pragma unroll
            for (int qt = 0; qt < 3; qt++) {
                int q = qt * 16 + l15;
                b2v[qt] = (q < OUT) ? b2[q] : 0.f;
            }
#pragma unroll
            for (int nt = 0; nt < NT; ++nt) {
                h8 A[4];
#pragma unroll
                for (int kt = 0; kt < 4; kt++) {
                    v4u av = {pkrtz(acc[2 * kt][nt][0], acc[2 * kt][nt][1]),
                              pkrtz(acc[2 * kt][nt][2], acc[2 * kt][nt][3]),
                              pkrtz(acc[2 * kt + 1][nt][0], acc[2 * kt + 1][nt][1]),
                              pkrtz(acc[2 * kt + 1][nt][2], acc[2 * kt + 1][nt][3])};
                    A[kt] = __builtin_bit_cast(h8, av);
                }
                const int tb = (R == 128) ? wv * 32 + nt * 16 : (R == 64) ? wv * 16 : 0;
#pragma unroll
                for (int qt = 0; qt < 3; ++qt) {
                    f32x4 o = {0.f, 0.f, 0.f, 0.f};
#pragma unroll
                    for (int kt = 0; kt < 4; kt++) {
                        v4u wvv = ((const v4u*)w2f)[(kt * 3 + qt) * 64 + lane];
                        o = __builtin_amdgcn_mfma_f32_16x16x32_f16(
                            A[kt], __builtin_bit_cast(h8, wvv), o, 0, 0, 0);
                    }
                    int q = qt * 16 + l15;
                    if (MODE == 0) {
                        if (q < OUT) {
#pragma unroll
                            for (int r = 0; r < 4; r++) {
                                int row = tb + l16 * 4 + r;
                                float v = o[r] + b2v[qt];
                                v = fmaxf(v, 0.01f * v);
                                cdst[row * CLDS + q] = f2h(v);
                            }
                        }
                    } else {
                        float s = 0.f;
#pragma unroll
                        for (int r = 0; r < 4; r++) {
                            float v = o[r] + b2v[qt];
                            s += fmaxf(v, 0.01f * v);
                        }
                        if (MODE == 1) {
                            if (q < OUT) {
                                int p = pbase + (tb >> 2) + l16;
                                cdst[p * CLDS + q] = f2h(s);
                            }
                        } else {
                            if (q < OUT && lane < 16) gout[q] = s;  // parent 0
                        }
                    }
                }
            }
        }
        __syncthreads();  // one barrier per pass: child buffer handoff
    };

    run_pass(ic<128>{}, ic<4>{}, ic<0>{}, dL0, lout, lout, 0, nullptr);
    run_pass(ic<128>{}, ic<6>{}, ic<1>{}, dD0, lout, d3o, 0, nullptr);
    run_pass(ic<128>{}, ic<4>{}, ic<0>{}, dL1, lout, lout, 0, nullptr);
    run_pass(ic<128>{}, ic<6>{}, ic<1>{}, dD1, lout, d3o, 32, nullptr);
    run_pass(ic<64>{}, ic<6>{}, ic<1>{}, dd2, d3o, d2o, 0, nullptr);
    run_pass(ic<16>{}, ic<6>{}, ic<1>{}, dd1, d2o, d1o, 0, nullptr);
    run_pass(ic<4>{}, ic<6>{}, ic<2>{}, dd0, d1o, nullptr, 0,
             out + (size_t)b * 40);
}

extern "C" void kernel_launch(void* const* d_in, const int* in_sizes, int n_in,
                              void* d_out, int out_size, void* d_ws, size_t ws_size,
                              hipStream_t stream) {
    const float* node_msg = (const float*)d_in[0];
    const float* bonds = (const float*)d_in[1];
    const float* W1 = (const float*)d_in[2];
    const float* b1 = (const float*)d_in[3];
    const float* W2 = (const float*)d_in[4];
    const float* b2 = (const float*)d_in[5];
    float* out = (float*)d_out;

    char* ws = (char*)d_ws;
    unsigned short* w1f = (unsigned short*)ws;            // 128*192*2 = 49152 B
    unsigned int* w2f = (unsigned int*)(ws + 49152);      // 12*64*16 = 12288 B

    prep_w1<<<96, 256, 0, stream>>>(W1, w1f);
    prep_w2<<<1, 256, 0, stream>>>(W2, w2f);
    tree_mlp<<<2048, 256, 0, stream>>>(node_msg, bonds, w1f, w2f, b1, b2, out);
}

// Round 9
// 246.587 us; speedup vs baseline: 1.8698x; 1.8698x over previous
//
#include <hip/hip_runtime.h>
#include <hip/hip_bf16.h>
#include <cstddef>

// K=2048, B=4, D=5, ATOM=125, BOND=12, HID=125, OUT=40
// NOFF = [0, 2048, 10240, 43008, 175104, 699392]
// BOFF = [0, 8192, 40960, 172032, 696320]
//
// 5 split level-kernels (full parallelism per level), each a small GEMM:
//   H^T = W1f(A-frag) x X(B-frag) via mfma_f32_16x16x32_f16, then layer2
//   from registers (W2 frag-packed, validated r3/r6 mapping).
// Pipeline (T3/T4-lite): double-buffered LDS X/W; per chunk
//   [issue c_{j+2} -> regs] [MFMA c_j] [ds_write c_{j+1}] [lgkmcnt(0); s_barrier]
// The barrier does NOT drain vmcnt -- c_{j+2}'s global loads stay in flight
// (compiler inserts counted vmcnt at the ds_write). One barrier per chunk.
// f16 everywhere (validated r6; RNE packing -- NOT cvt_pkrtz which is RTZ).
// k' layout (192): [0,125) msg, [125,128) 0, [128,140) bond, [140,144) 0,
//   [144,184) child, [184,192) 0.  Intermediates f16 [row][40] in ws.

typedef __attribute__((ext_vector_type(8))) _Float16 h8;
typedef __attribute__((ext_vector_type(4))) float f32x4;
typedef __attribute__((ext_vector_type(4))) unsigned int v4u;

static constexpr int HID = 125, OUT = 40;
static constexpr int XS = 40;  // LDS row stride (f16): 80B, 16B-aligned, 2-way banks

__device__ __forceinline__ unsigned short f2h(float x) {
    _Float16 h = (_Float16)x;  // RNE
    return __builtin_bit_cast(unsigned short, h);
}
__device__ __forceinline__ unsigned int pkh(float a, float b) {
    return (unsigned int)f2h(a) | ((unsigned int)f2h(b) << 16);
}

// W1 plane: [128 hid][192 k'] f16, k' remapped per layout above.
__global__ void prep_w1(const float* __restrict__ W1, unsigned short* __restrict__ w1f) {
    int idx = blockIdx.x * 256 + threadIdx.x;
    if (idx >= 128 * 192) return;
    int hid = idx / 192, kp = idx % 192;
    int k = (kp < 125) ? kp
          : (kp >= 128 && kp < 140) ? kp - 3
          : (kp >= 144 && kp < 184) ? kp - 7 : -1;
    float v = (k >= 0 && hid < HID) ? W1[(size_t)k * HID + hid] : 0.f;
    w1f[idx] = f2h(v);
}

// W2 frag-packed (layer2 B), validated mapping:
// frag fr = kt*3+qt; lane ln; elem j: hid = kt*32 + 16*(j>>2) + (ln>>4)*4 + (j&3),
// q = qt*16 + (ln&15). 4 u32 per (fr,lane).
__global__ void prep_w2(const float* __restrict__ W2, unsigned int* __restrict__ w2f) {
    int t = threadIdx.x;
    for (int task = t; task < 12 * 64; task += 256) {
        int ln = task & 63, fr = task >> 6;
        int kt = fr / 3, qt = fr % 3;
        int q = qt * 16 + (ln & 15);
        unsigned int w[4];
#pragma unroll
        for (int jp = 0; jp < 4; jp++) {
            unsigned short e[2];
#pragma unroll
            for (int s = 0; s < 2; s++) {
                int j = jp * 2 + s;
                int hid = kt * 32 + ((j >> 2) << 4) + ((ln >> 4) << 2) + (j & 3);
                float v = (hid < HID && q < OUT) ? W2[(size_t)hid * OUT + q] : 0.f;
                e[s] = f2h(v);
            }
            w[jp] = (unsigned int)e[0] | ((unsigned int)e[1] << 16);
        }
        v4u val = {w[0], w[1], w[2], w[3]};
        ((v4u*)w2f)[fr * 64 + ln] = val;
    }
}

// MODE 0: leaf (msg by row, per-row f16 out). MODE 1: mid (msg by row>>2,
// bond+child, sibling-summed f16 out). MODE 2: final (like 1, fp32 out).
template <int NC, int MODE>
__global__ void __launch_bounds__(256, 3)
level_k(const float* __restrict__ msg, const float* __restrict__ bonds,
        const unsigned short* __restrict__ child,
        const unsigned short* __restrict__ w1f, const unsigned int* __restrict__ w2f,
        const float* __restrict__ b1, const float* __restrict__ b2,
        void* __restrict__ outp) {
    __shared__ __align__(16) unsigned short Xb[2][128 * XS];
    __shared__ __align__(16) unsigned short Wb[2][128 * XS];

    const int tid = threadIdx.x;
    const int lane = tid & 63;
    const int wv = tid >> 6;
    const int l15 = tid & 15;
    const int l16 = (tid >> 4) & 3;
    const int c4 = tid & 3;    // X stager col-group (8 cols)
    const int rw = tid >> 2;   // X stager row 0..63 (and +64)
    const int wr_ = tid >> 1;  // W stager hid row
    const int whf = tid & 1;   // W stager half (16 k')
    const int base = blockIdx.x * 128;

    float fst[2][2][8];  // [set][p][i] msg/bond floats
    v4u cst[2][2];       // [set][p]    child raw f16x8
    v4u wst[2][2];       // [set][half] W chunk

    auto issue = [&](int j, int s) {
        const unsigned short* gw = w1f + (size_t)wr_ * 192 + j * 32 + whf * 16;
        wst[s][0] = *(const v4u*)gw;
        wst[s][1] = *(const v4u*)(gw + 8);
#pragma unroll
        for (int p = 0; p < 2; p++) {
            int row = base + rw + 64 * p;
            if (j <= 3) {
                int mr = (MODE == 0) ? row : (row >> 2);
                const float* mp = msg + (size_t)mr * 125;
#pragma unroll
                for (int i = 0; i < 8; i++) {
                    int k = j * 32 + c4 * 8 + i;
                    fst[s][p][i] = (k < 125) ? mp[k] : 0.f;  // uniform-true for j<3
                }
            } else if (j == 4) {
                if (c4 < 2) {
                    const float* bp = bonds + (size_t)row * 12;
#pragma unroll
                    for (int i = 0; i < 8; i++) {
                        int c = c4 * 8 + i;
                        fst[s][p][i] = (c < 12) ? bp[c] : 0.f;
                    }
                } else {
                    cst[s][p] = *(const v4u*)&child[(size_t)row * 40 + (c4 - 2) * 8];
                }
            } else {  // j == 5
                if (c4 < 3) {
                    cst[s][p] = *(const v4u*)&child[(size_t)row * 40 + 16 + c4 * 8];
                } else {
                    v4u z = {0, 0, 0, 0};
                    cst[s][p] = z;
                }
            }
        }
    };

    auto stage = [&](int j, int s, int buf) {
        *(v4u*)&Wb[buf][wr_ * XS + whf * 16] = wst[s][0];
        *(v4u*)&Wb[buf][wr_ * XS + whf * 16 + 8] = wst[s][1];
#pragma unroll
        for (int p = 0; p < 2; p++) {
            int row = rw + 64 * p;
            unsigned short* slot = &Xb[buf][row * XS + c4 * 8];
            if (j <= 3) {
                v4u val = {pkh(fst[s][p][0], fst[s][p][1]), pkh(fst[s][p][2], fst[s][p][3]),
                           pkh(fst[s][p][4], fst[s][p][5]), pkh(fst[s][p][6], fst[s][p][7])};
                *(v4u*)slot = val;
            } else if (j == 4) {
                if (c4 < 2) {
                    v4u val = {pkh(fst[s][p][0], fst[s][p][1]), pkh(fst[s][p][2], fst[s][p][3]),
                               pkh(fst[s][p][4], fst[s][p][5]), pkh(fst[s][p][6], fst[s][p][7])};
                    *(v4u*)slot = val;
                } else {
                    *(v4u*)slot = cst[s][p];
                }
            } else {
                *(v4u*)slot = cst[s][p];  // c4==3 staged as zeros at issue
            }
        }
    };

    f32x4 acc[8][2];
#pragma unroll
    for (int mt = 0; mt < 8; mt++) {
        f32x4 bi;
#pragma unroll
        for (int r = 0; r < 4; r++) {
            int h_ = mt * 16 + l16 * 4 + r;
            bi[r] = (h_ < HID) ? b1[h_] : 0.f;
        }
        acc[mt][0] = bi;
        acc[mt][1] = bi;
    }

    // ---- pipelined layer 1 ----
    issue(0, 0);
    issue(1, 1);
    stage(0, 0, 0);
    asm volatile("s_waitcnt lgkmcnt(0)\n\ts_barrier" ::: "memory");

#pragma unroll
    for (int j = 0; j < NC; ++j) {
        if (j + 2 < NC) issue(j + 2, j & 1);  // overwrites set consumed before last barrier
        // MFMA chunk j from buf j&1
        {
            h8 xf0 = *(const h8*)&Xb[j & 1][(wv * 32 + l15) * XS + l16 * 8];
            h8 xf1 = *(const h8*)&Xb[j & 1][(wv * 32 + 16 + l15) * XS + l16 * 8];
#pragma unroll
            for (int mt = 0; mt < 8; ++mt) {
                h8 wf = *(const h8*)&Wb[j & 1][(mt * 16 + l15) * XS + l16 * 8];
                acc[mt][0] = __builtin_amdgcn_mfma_f32_16x16x32_f16(wf, xf0, acc[mt][0], 0, 0, 0);
                acc[mt][1] = __builtin_amdgcn_mfma_f32_16x16x32_f16(wf, xf1, acc[mt][1], 0, 0, 0);
            }
        }
        if (j + 1 < NC) {
            stage(j + 1, (j + 1) & 1, (j + 1) & 1);  // counted vmcnt wait here
            asm volatile("s_waitcnt lgkmcnt(0)\n\ts_barrier" ::: "memory");
        }
    }

    // ---- leaky_relu on h ----
#pragma unroll
    for (int mt = 0; mt < 8; mt++)
#pragma unroll
        for (int nt = 0; nt < 2; nt++)
#pragma unroll
            for (int r = 0; r < 4; r++)
                acc[mt][nt][r] = fmaxf(acc[mt][nt][r], 0.01f * acc[mt][nt][r]);

    // ---- layer 2 (registers only; validated construction) ----
    float b2v[3];
#pragma unroll
    for (int qt = 0; qt < 3; qt++) {
        int q = qt * 16 + l15;
        b2v[qt] = (q < OUT) ? b2[q] : 0.f;
    }
#pragma unroll
    for (int nt = 0; nt < 2; ++nt) {
        h8 A[4];
#pragma unroll
        for (int kt = 0; kt < 4; kt++) {
            v4u av = {pkh(acc[2 * kt][nt][0], acc[2 * kt][nt][1]),
                      pkh(acc[2 * kt][nt][2], acc[2 * kt][nt][3]),
                      pkh(acc[2 * kt + 1][nt][0], acc[2 * kt + 1][nt][1]),
                      pkh(acc[2 * kt + 1][nt][2], acc[2 * kt + 1][nt][3])};
            A[kt] = __builtin_bit_cast(h8, av);
        }
        const int tb = wv * 32 + nt * 16;
#pragma unroll
        for (int qt = 0; qt < 3; ++qt) {
            f32x4 o = {0.f, 0.f, 0.f, 0.f};
#pragma unroll
            for (int kt = 0; kt < 4; kt++) {
                v4u wvv = ((const v4u*)w2f)[(kt * 3 + qt) * 64 + lane];
                o = __builtin_amdgcn_mfma_f32_16x16x32_f16(
                    A[kt], __builtin_bit_cast(h8, wvv), o, 0, 0, 0);
            }
            int q = qt * 16 + l15;
            if (MODE == 0) {
                unsigned short* ob = (unsigned short*)outp;
                if (q < OUT) {
#pragma unroll
                    for (int r = 0; r < 4; r++) {
                        int row = base + tb + l16 * 4 + r;
                        float v = o[r] + b2v[qt];
                        v = fmaxf(v, 0.01f * v);
                        ob[(size_t)row * 40 + q] = f2h(v);
                    }
                }
            } else {
                float s = 0.f;
#pragma unroll
                for (int r = 0; r < 4; r++) {
                    float v = o[r] + b2v[qt];
                    s += fmaxf(v, 0.01f * v);
                }
                if (q < OUT) {
                    int p = (base >> 2) + (tb >> 2) + l16;
                    if (MODE == 1)
                        ((unsigned short*)outp)[(size_t)p * 40 + q] = f2h(s);
                    else
                        ((float*)outp)[(size_t)p * 40 + q] = s;
                }
            }
        }
    }
}

extern "C" void kernel_launch(void* const* d_in, const int* in_sizes, int n_in,
                              void* d_out, int out_size, void* d_ws, size_t ws_size,
                              hipStream_t stream) {
    const float* node_msg = (const float*)d_in[0];
    const float* bonds = (const float*)d_in[1];
    const float* W1 = (const float*)d_in[2];
    const float* b1 = (const float*)d_in[3];
    const float* W2 = (const float*)d_in[4];
    const float* b2 = (const float*)d_in[5];
    float* out = (float*)d_out;

    char* ws = (char*)d_ws;
    unsigned short* bufA = (unsigned short*)ws;                   // 524288*40 f16 = 41943040 B
    unsigned short* bufB = (unsigned short*)(ws + 41943040);      // 131072*40 f16 = 10485760 B
    unsigned short* w1f = (unsigned short*)(ws + 52428800);       // 49152 B
    unsigned int* w2f = (unsigned int*)(ws + 52428800 + 49152);   // 12288 B

    prep_w1<<<96, 256, 0, stream>>>(W1, w1f);
    prep_w2<<<1, 256, 0, stream>>>(W2, w2f);

    // leaf (d=4): 524288 rows -> bufA
    level_k<4, 0><<<4096, 256, 0, stream>>>(
        node_msg + (size_t)175104 * 125, nullptr, nullptr, w1f, w2f, b1, b2, bufA);
    // d=3: 524288 edges -> 131072 parents -> bufB
    level_k<6, 1><<<4096, 256, 0, stream>>>(
        node_msg + (size_t)43008 * 125, bonds + (size_t)172032 * 12, bufA,
        w1f, w2f, b1, b2, bufB);
    // d=2: 131072 edges -> 32768 parents -> bufA (reuse)
    level_k<6, 1><<<1024, 256, 0, stream>>>(
        node_msg + (size_t)10240 * 125, bonds + (size_t)40960 * 12, bufB,
        w1f, w2f, b1, b2, bufA);
    // d=1: 32768 edges -> 8192 parents -> bufB (reuse)
    level_k<6, 1><<<256, 256, 0, stream>>>(
        node_msg + (size_t)2048 * 125, bonds + (size_t)8192 * 12, bufA,
        w1f, w2f, b1, b2, bufB);
    // d=0: 8192 edges -> 2048 parents -> out (fp32)
    level_k<6, 2><<<64, 256, 0, stream>>>(
        node_msg, bonds, bufB, w1f, w2f, b1, b2, out);
}